// Round 18
// baseline (60.403 us; speedup 1.0000x reference)
//
#include <hip/hip_runtime.h>
#include <math.h>

#define T_ 12
#define CIN_ 16
#define CE_ 8
#define HID_ 32
#define MAXD 32   // slots/node; in-degree ~ Poisson(10), P(deg>32) ~ 1e-8/node

typedef __attribute__((ext_vector_type(8))) short short8;
typedef __attribute__((ext_vector_type(4))) float f32x4;

__device__ __forceinline__ int rli(int v, int l) { return __builtin_amdgcn_readlane(v, l); }
__device__ __forceinline__ float rlf(float v, int l) {
    return __int_as_float(__builtin_amdgcn_readlane(__float_as_int(v), l));
}
__device__ __forceinline__ unsigned short f2bf(float f) {
    unsigned u = __float_as_uint(f);
    return (unsigned short)((u + 0x7fffu + ((u >> 16) & 1u)) >> 16);   // RNE
}
__device__ __forceinline__ float bf2f(unsigned short s) { return __uint_as_float((unsigned)s << 16); }
__device__ __forceinline__ float bflo(unsigned u) { return __uint_as_float(u << 16); }
__device__ __forceinline__ float bfhi(unsigned u) { return __uint_as_float(u & 0xffff0000u); }

__device__ __forceinline__ float gatef(float r, float u) {
    float S  = __builtin_amdgcn_rcpf(1.f + __expf(r));                    // 1 - sigmoid(r)
    float HC = 1.f - 2.f * __builtin_amdgcn_rcpf(__expf(2.f * u) + 1.f); // tanh(u), inf-safe
    return S * HC;
}

// ---- transpose x + bucket build (cnt pre-zeroed by memset) + weight prep ---
// B-frag: lane holds B[k=(lane>>4)*8+j][col=b*16+(lane&15)], j=0..7.
// Layer 1 weight rows permuted: h stores channel c at position q=2*(c%16)+(c/16),
// so actual_k(q) = (q>>1) | ((q&1)<<4).

__global__ void k_txp(const float* __restrict__ x, unsigned short* __restrict__ Xt,
                      int* __restrict__ cnt, int N,
                      const int* __restrict__ src, const int* __restrict__ dst, int E,
                      int2* __restrict__ bucket,
                      const float* __restrict__ Wg0, const float* __restrict__ Wu0,
                      const float* __restrict__ bg0, const float* __restrict__ bu0,
                      const float* __restrict__ Weg0, const float* __restrict__ Weu0,
                      const float* __restrict__ Wg1, const float* __restrict__ Wu1,
                      const float* __restrict__ bg1, const float* __restrict__ bu1,
                      const float* __restrict__ Weg1, const float* __restrict__ Weu1,
                      short8* __restrict__ BHi, short8* __restrict__ BLo,
                      float* __restrict__ WeD, float* __restrict__ biasD) {
    int id = blockIdx.x * blockDim.x + threadIdx.x;
    // ---- bucket build (independent of transpose; cnt zeroed by memset) ----
    if (id < E) {
        int s = src[id], d = dst[id];
        int pos = atomicAdd(&cnt[d], 1);
        if (pos < MAXD) bucket[(size_t)d * MAXD + pos] = make_int2(s, id);
    }
    // ---- transpose ----
    int total = N * T_ * 4;
    if (id < total) {
        int n = id / (T_ * 4);
        int r = id - n * (T_ * 4);
        int t = r >> 2, c4 = r & 3;
        float4 v = ((const float4*)x)[((size_t)t * N + n) * 4 + c4];
        ushort4 o;
        o.x = f2bf(v.x); o.y = f2bf(v.y); o.z = f2bf(v.z); o.w = f2bf(v.w);
        *((ushort4*)(Xt + (size_t)n * (T_ * CIN_) + t * CIN_ + c4 * 4)) = o;
    }
    // ---- weight prep on blocks 0,1 (L = blockIdx.x) ----
    if (blockIdx.x >= 2) return;
    int L = blockIdx.x;
    int tid = threadIdx.x;
    int b = tid >> 6, lane = tid & 63;
    int cl = lane & 15;
    int c = b * 16 + cl;                       // cat channel (R half | update half)
    const float* Wg  = L ? Wg1 : Wg0;
    const float* Wu  = L ? Wu1 : Wu0;
    const float* bgp = L ? bg1 : bg0;
    const float* bup = L ? bu1 : bu0;
    const float* Weg = L ? Weg1 : Weg0;
    const float* Weu = L ? Weu1 : Weu0;
    const float* wcol; int wstr;
    if (c < 32) { wcol = Wg + 32 + c; wstr = 64; }     // gate R half: Wg[:,32+c]
    else        { wcol = Wu + (c - 32); wstr = 32; }   // update: Wu[:,c-32]
    int k0 = (lane >> 4) * 8;
    short8 hi8, lo8;
#pragma unroll
    for (int j = 0; j < 8; j++) {
        int kp = k0 + j;
        int ak; bool v;
        if (L) { ak = (kp >> 1) | ((kp & 1) << 4); v = true; }   // de-interleave perm
        else   { ak = kp; v = (kp < CIN_); }                     // K=16, pad zero
        float w = v ? wcol[(size_t)ak * wstr] : 0.f;
        unsigned short hh = f2bf(w);
        unsigned short ll = f2bf(w - bf2f(hh));
        hi8[j] = (short)hh; lo8[j] = (short)ll;
    }
    int idx = (L * 4 + b) * 64 + lane;
    BHi[idx] = hi8;
    BLo[idx] = lo8;
#pragma unroll
    for (int j = 0; j < CE_; j++)
        WeD[(size_t)idx * 8 + j] = (c < 32) ? Weg[j * 64 + 32 + c] : Weu[j * 32 + (c - 32)];
    biasD[idx] = (c < 32) ? bgp[32 + c] : bup[c - 32];
}

// ---- fused layer: one node per wave, gather -> MFMA -> gate ----------------
// feat rows: l0 = Xt [192 shorts], l1 = h [384 shorts, channel-interleaved].
// A-frag: lane holds feat_row[t=(lane&15)][k=(lane>>4)*8+j] (t>=12 garbage, discarded).

template<int L0>
__global__ __launch_bounds__(256, 4)
void k_layer(const unsigned short* __restrict__ feat,
             const int* __restrict__ cnt, const int2* __restrict__ bucket,
             int2* __restrict__ gbuf, const float* __restrict__ eattr,
             float* __restrict__ eagg8,
             const short8* __restrict__ bhi, const short8* __restrict__ blo,
             const float* __restrict__ WeDp, const float* __restrict__ biasDp,
             void* __restrict__ outp, int N)
{
    int tid = threadIdx.x, lane = tid & 63;
    int n = (blockIdx.x * 256 + tid) >> 6;
    if (n >= N) return;
    int cl = lane & 15, tq = lane >> 4;

    // ---- edge metadata + e8 ----
    int srcl = 0; float nmv = 0.f;
    float e8[CE_];
    int degn;
    if constexpr (L0) {
        int degf = cnt[n];
        degn = min(degf, MAXD);
        int eid = 0;
        if (lane < 32) {
            int2 me = bucket[(size_t)n * MAXD + lane];
            bool valid = lane < degn;
            srcl = valid ? me.x : 0;
            eid  = valid ? me.y : 0;
            nmv  = valid ? rsqrtf((float)max(cnt[srcl], 1) * (float)max(degf, 1)) : 0.f;
            gbuf[(size_t)n * MAXD + lane] = make_int2(srcl, __float_as_int(nmv));
        }
        const float4* ep = (const float4*)(eattr + (size_t)eid * CE_);
        float4 q0 = make_float4(0,0,0,0), q1 = q0;
        if (lane < 32) { q0 = ep[0]; q1 = ep[1]; }
        float a8[8] = { nmv*q0.x, nmv*q0.y, nmv*q0.z, nmv*q0.w,
                        nmv*q1.x, nmv*q1.y, nmv*q1.z, nmv*q1.w };
#pragma unroll
        for (int o = 16; o; o >>= 1) {
#pragma unroll
            for (int j = 0; j < 8; j++) a8[j] += __shfl_xor(a8[j], o, 64);
        }
#pragma unroll
        for (int j = 0; j < 8; j++) e8[j] = rlf(a8[j], 0);
        if (lane == 0) {
            float4* eo = (float4*)(eagg8 + (size_t)n * CE_);
            eo[0] = make_float4(e8[0], e8[1], e8[2], e8[3]);
            eo[1] = make_float4(e8[4], e8[5], e8[6], e8[7]);
        }
    } else {
        if (lane < 32) {
            int2 gv = gbuf[(size_t)n * MAXD + lane];
            srcl = gv.x; nmv = __int_as_float(gv.y);
        }
        unsigned long long bal = __ballot(nmv != 0.f);
        degn = __popcll(bal);
        const float* e8p = eagg8 + (size_t)n * CE_;
#pragma unroll
        for (int j = 0; j < 8; j++) e8[j] = e8p[j];
    }

    // ---- B-fragments + per-channel base (f32) ----
    short8 bh[4], bl_[4];
#pragma unroll
    for (int b = 0; b < 4; b++) { bh[b] = bhi[b * 64 + lane]; bl_[b] = blo[b * 64 + lane]; }
    float base[4];
#pragma unroll
    for (int b = 0; b < 4; b++) {
        float s = biasDp[b * 64 + lane];
        const float* wd = WeDp + (size_t)(b * 64 + lane) * 8;
#pragma unroll
        for (int j = 0; j < CE_; j++) s = fmaf(e8[j], wd[j], s);
        base[b] = s;
    }

    // ---- gather (A-fragment-shaped, coalesced; garbage lanes clamped to row start) ----
    constexpr int ROWS = L0 ? (T_ * CIN_) : (T_ * HID_);   // 192 | 384 shorts
    int myoff = L0 ? ((cl < 12 ? cl * CIN_ : 0) + tq * 8)
                   : ((cl < 12 ? cl * HID_ : 0) + tq * 8);
    bool ldon = L0 ? (lane < 32) : true;
    float acc[8] = {0, 0, 0, 0, 0, 0, 0, 0};
    for (int eb = 0; eb < degn; eb += 4) {
        uint4 v[4]; float nn[4];
#pragma unroll
        for (int ii = 0; ii < 4; ii++) {
            int i = eb + ii;                       // wave-uniform
            int s = rli(srcl, i & 31);
            nn[ii] = rlf(nmv, i & 31);             // phantom slots carry nm=0
            v[ii] = make_uint4(0, 0, 0, 0);
            if (ldon) v[ii] = *(const uint4*)(feat + (size_t)s * ROWS + myoff);
        }
#pragma unroll
        for (int ii = 0; ii < 4; ii++) {
            acc[0] = fmaf(nn[ii], bflo(v[ii].x), acc[0]);
            acc[1] = fmaf(nn[ii], bfhi(v[ii].x), acc[1]);
            acc[2] = fmaf(nn[ii], bflo(v[ii].y), acc[2]);
            acc[3] = fmaf(nn[ii], bfhi(v[ii].y), acc[3]);
            acc[4] = fmaf(nn[ii], bflo(v[ii].z), acc[4]);
            acc[5] = fmaf(nn[ii], bfhi(v[ii].z), acc[5]);
            acc[6] = fmaf(nn[ii], bflo(v[ii].w), acc[6]);
            acc[7] = fmaf(nn[ii], bfhi(v[ii].w), acc[7]);
        }
    }

    // ---- A-fragments (hi/lo split) + MFMA ----
    short8 ah, al;
#pragma unroll
    for (int j = 0; j < 8; j++) {
        unsigned short hh = f2bf(acc[j]);
        ah[j] = (short)hh;
        al[j] = (short)f2bf(acc[j] - bf2f(hh));
    }
    f32x4 D[4];
#pragma unroll
    for (int b = 0; b < 4; b++) {
        f32x4 C = { base[b], base[b], base[b], base[b] };
        C = __builtin_amdgcn_mfma_f32_16x16x32_bf16(al, bh[b],  C, 0, 0, 0);
        C = __builtin_amdgcn_mfma_f32_16x16x32_bf16(ah, bl_[b], C, 0, 0, 0);
        C = __builtin_amdgcn_mfma_f32_16x16x32_bf16(ah, bh[b],  C, 0, 0, 0);
        D[b] = C;
    }

    // ---- gate + write: D row = tq*4+j = t (t>=12 discarded); col cl ----
    if (tq < 3) {
#pragma unroll
        for (int j = 0; j < 4; j++) {
            int t = tq * 4 + j;
            float o0 = gatef(D[0][j], D[2][j]);   // hidden ch cl
            float o1 = gatef(D[1][j], D[3][j]);   // hidden ch 16+cl
            if constexpr (L0) {
                o0 = fmaxf(o0, 0.f); o1 = fmaxf(o1, 0.f);
                unsigned pv = (unsigned)f2bf(o0) | ((unsigned)f2bf(o1) << 16);
                *(unsigned*)((unsigned short*)outp + (size_t)n * (T_ * HID_) + t * HID_ + 2 * cl) = pv;
            } else {
                float* op = (float*)outp;
                op[((size_t)t * N + n) * HID_ + cl] = o0;
                op[((size_t)t * N + n) * HID_ + 16 + cl] = o1;
            }
        }
    }
}

// ---- launch ---------------------------------------------------------------

extern "C" void kernel_launch(void* const* d_in, const int* in_sizes, int n_in,
                              void* d_out, int out_size, void* d_ws, size_t ws_size,
                              hipStream_t stream) {
    const float* x     = (const float*)d_in[0];
    const int*   eidx  = (const int*)d_in[1];
    const float* eattr = (const float*)d_in[2];
    const float* Wg0 = (const float*)d_in[3], *Weg0 = (const float*)d_in[4], *bg0 = (const float*)d_in[5];
    const float* Wu0 = (const float*)d_in[6], *Weu0 = (const float*)d_in[7], *bu0 = (const float*)d_in[8];
    const float* Wg1 = (const float*)d_in[9], *Weg1 = (const float*)d_in[10], *bg1 = (const float*)d_in[11];
    const float* Wu1 = (const float*)d_in[12], *Weu1 = (const float*)d_in[13], *bu1 = (const float*)d_in[14];

    int N = in_sizes[0] / (T_ * CIN_);
    int E = in_sizes[1] / 2;
    const int* src = eidx;
    const int* dst = eidx + E;

    char* ws = (char*)d_ws;
    size_t off = 0;
    auto alloc = [&](size_t bytes) -> void* {
        off = (off + 255) & ~(size_t)255;
        void* p = ws + off;
        off += bytes;
        return p;
    };
    int*            cnt    = (int*)alloc((size_t)N * 4);
    int2*           bucket = (int2*)alloc((size_t)N * MAXD * 8);
    int2*           gbuf   = (int2*)alloc((size_t)N * MAXD * 8);
    float*          eagg8  = (float*)alloc((size_t)N * CE_ * 4);
    unsigned short* Xt     = (unsigned short*)alloc((size_t)N * T_ * CIN_ * 2 + 1024);
    unsigned short* h      = (unsigned short*)alloc((size_t)N * T_ * HID_ * 2 + 1024);
    short8*         BHi    = (short8*)alloc(2 * 4 * 64 * 16);
    short8*         BLo    = (short8*)alloc(2 * 4 * 64 * 16);
    float*          WeD    = (float*)alloc(2 * 4 * 64 * 8 * 4);
    float*          biasD  = (float*)alloc(2 * 4 * 64 * 4);
    (void)ws_size; (void)n_in; (void)out_size;

    // 1) zero in-degree counters (tiny), 2) transpose + prep + bucket build
    hipMemsetAsync(cnt, 0, (size_t)N * 4, stream);
    k_txp<<<(N * T_ * 4 + 255) / 256, 256, 0, stream>>>(x, Xt, cnt, N,
                                                        src, dst, E, bucket,
                                                        Wg0, Wu0, bg0, bu0, Weg0, Weu0,
                                                        Wg1, Wu1, bg1, bu1, Weg1, Weu1,
                                                        BHi, BLo, WeD, biasD);

    int blocks = (N + 3) / 4;
    k_layer<1><<<blocks, 256, 0, stream>>>(Xt, cnt, bucket, gbuf, eattr, eagg8,
                                           BHi, BLo, WeD, biasD, h, N);
    k_layer<0><<<blocks, 256, 0, stream>>>(h, cnt, bucket, gbuf, eattr, eagg8,
                                           BHi + 256, BLo + 256, WeD + 256 * 8, biasD + 256,
                                           (float*)d_out, N);
}

// Round 19
// 58.161 us; speedup vs baseline: 1.0385x; 1.0385x over previous
//
#include <hip/hip_runtime.h>
#include <math.h>

#define T_ 12
#define CIN_ 16
#define CE_ 8
#define HID_ 32
#define MAXD 32   // slots/node; in-degree ~ Poisson(10), P(deg>32) ~ 1e-8/node

typedef __attribute__((ext_vector_type(8))) short short8;
typedef __attribute__((ext_vector_type(4))) float f32x4;

__device__ __forceinline__ int rli(int v, int l) { return __builtin_amdgcn_readlane(v, l); }
__device__ __forceinline__ float rlf(float v, int l) {
    return __int_as_float(__builtin_amdgcn_readlane(__float_as_int(v), l));
}
__device__ __forceinline__ unsigned short f2bf(float f) {
    unsigned u = __float_as_uint(f);
    return (unsigned short)((u + 0x7fffu + ((u >> 16) & 1u)) >> 16);   // RNE
}
__device__ __forceinline__ float bf2f(unsigned short s) { return __uint_as_float((unsigned)s << 16); }
__device__ __forceinline__ float bflo(unsigned u) { return __uint_as_float(u << 16); }
__device__ __forceinline__ float bfhi(unsigned u) { return __uint_as_float(u & 0xffff0000u); }

__device__ __forceinline__ float gatef(float r, float u) {
    float S  = __builtin_amdgcn_rcpf(1.f + __expf(r));                    // 1 - sigmoid(r)
    float HC = 1.f - 2.f * __builtin_amdgcn_rcpf(__expf(2.f * u) + 1.f); // tanh(u), inf-safe
    return S * HC;
}

// ---- transpose x (zeroes cnt) + weight prep on blocks 0,1 ------------------
// B-frag: lane holds B[k=(lane>>4)*8+j][col=b*16+(lane&15)], j=0..7.
// Layer 1 weight rows permuted: h stores channel c at position q=2*(c%16)+(c/16),
// so actual_k(q) = (q>>1) | ((q&1)<<4).

__global__ void k_txp(const float* __restrict__ x, unsigned short* __restrict__ Xt,
                      int* __restrict__ cnt, int N,
                      const float* __restrict__ Wg0, const float* __restrict__ Wu0,
                      const float* __restrict__ bg0, const float* __restrict__ bu0,
                      const float* __restrict__ Weg0, const float* __restrict__ Weu0,
                      const float* __restrict__ Wg1, const float* __restrict__ Wu1,
                      const float* __restrict__ bg1, const float* __restrict__ bu1,
                      const float* __restrict__ Weg1, const float* __restrict__ Weu1,
                      short8* __restrict__ BHi, short8* __restrict__ BLo,
                      float* __restrict__ WeD, float* __restrict__ biasD) {
    int id = blockIdx.x * blockDim.x + threadIdx.x;
    if (id < N) cnt[id] = 0;
    int total = N * T_ * 4;
    if (id < total) {
        int n = id / (T_ * 4);
        int r = id - n * (T_ * 4);
        int t = r >> 2, c4 = r & 3;
        float4 v = ((const float4*)x)[((size_t)t * N + n) * 4 + c4];
        ushort4 o;
        o.x = f2bf(v.x); o.y = f2bf(v.y); o.z = f2bf(v.z); o.w = f2bf(v.w);
        *((ushort4*)(Xt + (size_t)n * (T_ * CIN_) + t * CIN_ + c4 * 4)) = o;
    }
    // ---- weight prep on blocks 0,1 (L = blockIdx.x) ----
    if (blockIdx.x >= 2) return;
    int L = blockIdx.x;
    int tid = threadIdx.x;
    int b = tid >> 6, lane = tid & 63;
    int cl = lane & 15;
    int c = b * 16 + cl;                       // cat channel (R half | update half)
    const float* Wg  = L ? Wg1 : Wg0;
    const float* Wu  = L ? Wu1 : Wu0;
    const float* bgp = L ? bg1 : bg0;
    const float* bup = L ? bu1 : bu0;
    const float* Weg = L ? Weg1 : Weg0;
    const float* Weu = L ? Weu1 : Weu0;
    const float* wcol; int wstr;
    if (c < 32) { wcol = Wg + 32 + c; wstr = 64; }     // gate R half: Wg[:,32+c]
    else        { wcol = Wu + (c - 32); wstr = 32; }   // update: Wu[:,c-32]
    int k0 = (lane >> 4) * 8;
    short8 hi8, lo8;
#pragma unroll
    for (int j = 0; j < 8; j++) {
        int kp = k0 + j;
        int ak; bool v;
        if (L) { ak = (kp >> 1) | ((kp & 1) << 4); v = true; }   // de-interleave perm
        else   { ak = kp; v = (kp < CIN_); }                     // K=16, pad zero
        float w = v ? wcol[(size_t)ak * wstr] : 0.f;
        unsigned short hh = f2bf(w);
        unsigned short ll = f2bf(w - bf2f(hh));
        hi8[j] = (short)hh; lo8[j] = (short)ll;
    }
    int idx = (L * 4 + b) * 64 + lane;
    BHi[idx] = hi8;
    BLo[idx] = lo8;
#pragma unroll
    for (int j = 0; j < CE_; j++)
        WeD[(size_t)idx * 8 + j] = (c < 32) ? Weg[j * 64 + 32 + c] : Weu[j * 32 + (c - 32)];
    biasD[idx] = (c < 32) ? bgp[32 + c] : bup[c - 32];
}

// ---- bucket build ----------------------------------------------------------

__global__ void k_build(const int* __restrict__ src, const int* __restrict__ dst, int E,
                        int* __restrict__ cnt, int2* __restrict__ bucket) {
    int e = blockIdx.x * blockDim.x + threadIdx.x;
    if (e >= E) return;
    int s = src[e], d = dst[e];
    int pos = atomicAdd(&cnt[d], 1);
    if (pos < MAXD) bucket[(size_t)d * MAXD + pos] = make_int2(s, e);
}

// ---- fused layer: one node per wave, gather -> MFMA -> gate ----------------
// feat rows: l0 = Xt [192 shorts], l1 = h [384 shorts, channel-interleaved].
// A-frag: lane holds feat_row[t=(lane&15)][k=(lane>>4)*8+j] (t>=12 garbage, discarded).

template<int L0>
__global__ __launch_bounds__(256, 4)
void k_layer(const unsigned short* __restrict__ feat,
             const int* __restrict__ cnt, const int2* __restrict__ bucket,
             int2* __restrict__ gbuf, const float* __restrict__ eattr,
             float* __restrict__ eagg8,
             const short8* __restrict__ bhi, const short8* __restrict__ blo,
             const float* __restrict__ WeDp, const float* __restrict__ biasDp,
             void* __restrict__ outp, int N)
{
    int tid = threadIdx.x, lane = tid & 63;
    int n = (blockIdx.x * 256 + tid) >> 6;
    if (n >= N) return;
    int cl = lane & 15, tq = lane >> 4;

    // ---- edge metadata + e8 ----
    int srcl = 0; float nmv = 0.f;
    float e8[CE_];
    int degn;
    if constexpr (L0) {
        int degf = cnt[n];
        degn = min(degf, MAXD);
        int eid = 0;
        if (lane < 32) {
            int2 me = bucket[(size_t)n * MAXD + lane];
            bool valid = lane < degn;
            srcl = valid ? me.x : 0;
            eid  = valid ? me.y : 0;
            nmv  = valid ? rsqrtf((float)max(cnt[srcl], 1) * (float)max(degf, 1)) : 0.f;
            gbuf[(size_t)n * MAXD + lane] = make_int2(srcl, __float_as_int(nmv));
        }
        const float4* ep = (const float4*)(eattr + (size_t)eid * CE_);
        float4 q0 = make_float4(0,0,0,0), q1 = q0;
        if (lane < 32) { q0 = ep[0]; q1 = ep[1]; }
        float a8[8] = { nmv*q0.x, nmv*q0.y, nmv*q0.z, nmv*q0.w,
                        nmv*q1.x, nmv*q1.y, nmv*q1.z, nmv*q1.w };
#pragma unroll
        for (int o = 16; o; o >>= 1) {
#pragma unroll
            for (int j = 0; j < 8; j++) a8[j] += __shfl_xor(a8[j], o, 64);
        }
#pragma unroll
        for (int j = 0; j < 8; j++) e8[j] = rlf(a8[j], 0);
        if (lane == 0) {
            float4* eo = (float4*)(eagg8 + (size_t)n * CE_);
            eo[0] = make_float4(e8[0], e8[1], e8[2], e8[3]);
            eo[1] = make_float4(e8[4], e8[5], e8[6], e8[7]);
        }
    } else {
        if (lane < 32) {
            int2 gv = gbuf[(size_t)n * MAXD + lane];
            srcl = gv.x; nmv = __int_as_float(gv.y);
        }
        unsigned long long bal = __ballot(nmv != 0.f);
        degn = __popcll(bal);
        const float* e8p = eagg8 + (size_t)n * CE_;
#pragma unroll
        for (int j = 0; j < 8; j++) e8[j] = e8p[j];
    }

    // ---- B-fragments + per-channel base (f32) ----
    short8 bh[4], bl_[4];
#pragma unroll
    for (int b = 0; b < 4; b++) { bh[b] = bhi[b * 64 + lane]; bl_[b] = blo[b * 64 + lane]; }
    float base[4];
#pragma unroll
    for (int b = 0; b < 4; b++) {
        float s = biasDp[b * 64 + lane];
        const float* wd = WeDp + (size_t)(b * 64 + lane) * 8;
#pragma unroll
        for (int j = 0; j < CE_; j++) s = fmaf(e8[j], wd[j], s);
        base[b] = s;
    }

    // ---- gather (A-fragment-shaped, coalesced; garbage lanes clamped to row start) ----
    constexpr int ROWS = L0 ? (T_ * CIN_) : (T_ * HID_);   // 192 | 384 shorts
    int myoff = L0 ? ((cl < 12 ? cl * CIN_ : 0) + tq * 8)
                   : ((cl < 12 ? cl * HID_ : 0) + tq * 8);
    bool ldon = L0 ? (lane < 32) : true;
    float acc[8] = {0, 0, 0, 0, 0, 0, 0, 0};
    for (int eb = 0; eb < degn; eb += 4) {
        uint4 v[4]; float nn[4];
#pragma unroll
        for (int ii = 0; ii < 4; ii++) {
            int i = eb + ii;                       // wave-uniform
            int s = rli(srcl, i & 31);
            nn[ii] = rlf(nmv, i & 31);             // phantom slots carry nm=0
            v[ii] = make_uint4(0, 0, 0, 0);
            if (ldon) v[ii] = *(const uint4*)(feat + (size_t)s * ROWS + myoff);
        }
#pragma unroll
        for (int ii = 0; ii < 4; ii++) {
            acc[0] = fmaf(nn[ii], bflo(v[ii].x), acc[0]);
            acc[1] = fmaf(nn[ii], bfhi(v[ii].x), acc[1]);
            acc[2] = fmaf(nn[ii], bflo(v[ii].y), acc[2]);
            acc[3] = fmaf(nn[ii], bfhi(v[ii].y), acc[3]);
            acc[4] = fmaf(nn[ii], bflo(v[ii].z), acc[4]);
            acc[5] = fmaf(nn[ii], bfhi(v[ii].z), acc[5]);
            acc[6] = fmaf(nn[ii], bflo(v[ii].w), acc[6]);
            acc[7] = fmaf(nn[ii], bfhi(v[ii].w), acc[7]);
        }
    }

    // ---- A-fragments (hi/lo split) + MFMA ----
    short8 ah, al;
#pragma unroll
    for (int j = 0; j < 8; j++) {
        unsigned short hh = f2bf(acc[j]);
        ah[j] = (short)hh;
        al[j] = (short)f2bf(acc[j] - bf2f(hh));
    }
    f32x4 D[4];
#pragma unroll
    for (int b = 0; b < 4; b++) {
        f32x4 C = { base[b], base[b], base[b], base[b] };
        C = __builtin_amdgcn_mfma_f32_16x16x32_bf16(al, bh[b],  C, 0, 0, 0);
        C = __builtin_amdgcn_mfma_f32_16x16x32_bf16(ah, bl_[b], C, 0, 0, 0);
        C = __builtin_amdgcn_mfma_f32_16x16x32_bf16(ah, bh[b],  C, 0, 0, 0);
        D[b] = C;
    }

    // ---- gate + write: D row = tq*4+j = t (t>=12 discarded); col cl ----
    if (tq < 3) {
#pragma unroll
        for (int j = 0; j < 4; j++) {
            int t = tq * 4 + j;
            float o0 = gatef(D[0][j], D[2][j]);   // hidden ch cl
            float o1 = gatef(D[1][j], D[3][j]);   // hidden ch 16+cl
            if constexpr (L0) {
                o0 = fmaxf(o0, 0.f); o1 = fmaxf(o1, 0.f);
                unsigned pv = (unsigned)f2bf(o0) | ((unsigned)f2bf(o1) << 16);
                *(unsigned*)((unsigned short*)outp + (size_t)n * (T_ * HID_) + t * HID_ + 2 * cl) = pv;
            } else {
                float* op = (float*)outp;
                op[((size_t)t * N + n) * HID_ + cl] = o0;
                op[((size_t)t * N + n) * HID_ + 16 + cl] = o1;
            }
        }
    }
}

// ---- launch ---------------------------------------------------------------

extern "C" void kernel_launch(void* const* d_in, const int* in_sizes, int n_in,
                              void* d_out, int out_size, void* d_ws, size_t ws_size,
                              hipStream_t stream) {
    const float* x     = (const float*)d_in[0];
    const int*   eidx  = (const int*)d_in[1];
    const float* eattr = (const float*)d_in[2];
    const float* Wg0 = (const float*)d_in[3], *Weg0 = (const float*)d_in[4], *bg0 = (const float*)d_in[5];
    const float* Wu0 = (const float*)d_in[6], *Weu0 = (const float*)d_in[7], *bu0 = (const float*)d_in[8];
    const float* Wg1 = (const float*)d_in[9], *Weg1 = (const float*)d_in[10], *bg1 = (const float*)d_in[11];
    const float* Wu1 = (const float*)d_in[12], *Weu1 = (const float*)d_in[13], *bu1 = (const float*)d_in[14];

    int N = in_sizes[0] / (T_ * CIN_);
    int E = in_sizes[1] / 2;
    const int* src = eidx;
    const int* dst = eidx + E;

    char* ws = (char*)d_ws;
    size_t off = 0;
    auto alloc = [&](size_t bytes) -> void* {
        off = (off + 255) & ~(size_t)255;
        void* p = ws + off;
        off += bytes;
        return p;
    };
    int*            cnt    = (int*)alloc((size_t)N * 4);
    int2*           bucket = (int2*)alloc((size_t)N * MAXD * 8);
    int2*           gbuf   = (int2*)alloc((size_t)N * MAXD * 8);
    float*          eagg8  = (float*)alloc((size_t)N * CE_ * 4);
    unsigned short* Xt     = (unsigned short*)alloc((size_t)N * T_ * CIN_ * 2 + 1024);
    unsigned short* h      = (unsigned short*)alloc((size_t)N * T_ * HID_ * 2 + 1024);
    short8*         BHi    = (short8*)alloc(2 * 4 * 64 * 16);
    short8*         BLo    = (short8*)alloc(2 * 4 * 64 * 16);
    float*          WeD    = (float*)alloc(2 * 4 * 64 * 8 * 4);
    float*          biasD  = (float*)alloc(2 * 4 * 64 * 4);
    (void)ws_size; (void)n_in; (void)out_size;

    k_txp<<<(N * T_ * 4 + 255) / 256, 256, 0, stream>>>(x, Xt, cnt, N,
                                                        Wg0, Wu0, bg0, bu0, Weg0, Weu0,
                                                        Wg1, Wu1, bg1, bu1, Weg1, Weu1,
                                                        BHi, BLo, WeD, biasD);
    k_build<<<(E + 255) / 256, 256, 0, stream>>>(src, dst, E, cnt, bucket);

    int blocks = (N + 3) / 4;
    k_layer<1><<<blocks, 256, 0, stream>>>(Xt, cnt, bucket, gbuf, eattr, eagg8,
                                           BHi, BLo, WeD, biasD, h, N);
    k_layer<0><<<blocks, 256, 0, stream>>>(h, cnt, bucket, gbuf, eattr, eagg8,
                                           BHi + 256, BLo + 256, WeD + 256 * 8, biasD + 256,
                                           (float*)d_out, N);
}